// Round 1
// baseline (296.890 us; speedup 1.0000x reference)
//
#include <hip/hip_runtime.h>

typedef short bf16x8 __attribute__((ext_vector_type(8)));
typedef float f32x4 __attribute__((ext_vector_type(4)));

#define NSEQ 4096
#define BATCH 2
#define DIM 512
#define HEADS 8
#define NROWS (BATCH * NSEQ)   // 8192
#define QKVN (3 * DIM)         // 1536

__device__ __forceinline__ unsigned short f2bf(float f) {
  unsigned int u = __float_as_uint(f);
  u += 0x7fffu + ((u >> 16) & 1u);
  return (unsigned short)(u >> 16);
}
__device__ __forceinline__ float bf2f(unsigned short h) {
  return __uint_as_float(((unsigned int)h) << 16);
}
// swizzled LDS byte address for [row][128B] tiles (breaks 32-way conflicts)
__device__ __forceinline__ int swz(int row, int colb) {
  return row * 128 + (colb ^ ((row & 7) << 4));
}
__device__ __forceinline__ void gload16(const unsigned short* g, unsigned short* l) {
  __builtin_amdgcn_global_load_lds((const __attribute__((address_space(1))) unsigned int*)g,
                                   (__attribute__((address_space(3))) unsigned int*)l, 16, 0, 0);
}

// ---------------- cos/sin tables ----------------
__global__ __launch_bounds__(256) void k_tables(const float* __restrict__ rot,
                                                float* __restrict__ cosT,
                                                float* __restrict__ sinT) {
  int i = blockIdx.x * 256 + threadIdx.x;
  float f = rot[i];
  cosT[i] = cosf(f);
  sinT[i] = sinf(f);
}

// ---------------- fp32 -> bf16 weight convert ----------------
__global__ __launch_bounds__(256) void k_cvt(const float* __restrict__ src,
                                             unsigned short* __restrict__ dst, int n) {
  int i = blockIdx.x * 256 + threadIdx.x;
  if (i < n) dst[i] = f2bf(src[i]);
}

// ---------------- LayerNorm: one wave per row ----------------
__global__ __launch_bounds__(256) void k_ln(const float* __restrict__ x,
                                            const float* __restrict__ w,
                                            const float* __restrict__ bb,
                                            unsigned short* __restrict__ xn) {
  int row = blockIdx.x * 4 + (threadIdx.x >> 6);
  int lane = threadIdx.x & 63;
  const float* xr = x + (size_t)row * DIM;
  float v[8];
  float s = 0.f;
#pragma unroll
  for (int j = 0; j < 8; ++j) { v[j] = xr[lane + j * 64]; s += v[j]; }
#pragma unroll
  for (int m = 1; m < 64; m <<= 1) s += __shfl_xor(s, m);
  float mu = s * (1.0f / DIM);
  float q = 0.f;
#pragma unroll
  for (int j = 0; j < 8; ++j) { float d = v[j] - mu; q += d * d; }
#pragma unroll
  for (int m = 1; m < 64; m <<= 1) q += __shfl_xor(q, m);
  float rs = rsqrtf(q * (1.0f / DIM) + 1e-5f);
#pragma unroll
  for (int j = 0; j < 8; ++j) {
    int col = lane + j * 64;
    xn[(size_t)row * DIM + col] = f2bf((v[j] - mu) * rs * w[col] + bb[col]);
  }
}

// ---------------- GEMM: C[M][N] = A[M][K] * B[N][K]^T  (m97-style) ----------------
// EPI=0: bf16 store; EPI=1: fp32 store + bias
template <int EPI>
__global__ __launch_bounds__(256) void k_gemm(const unsigned short* __restrict__ A,
                                              const unsigned short* __restrict__ B,
                                              void* __restrict__ C,
                                              const float* __restrict__ bias,
                                              int M, int N, int K) {
  __shared__ __align__(16) unsigned short As[128 * 32];
  __shared__ __align__(16) unsigned short Bs[128 * 32];
  int bm = blockIdx.x, bn = blockIdx.y;
  int tid = threadIdx.x;
  int lane = tid & 63, w = tid >> 6;
  int wm = (w >> 1) << 6, wn = (w & 1) << 6;
  f32x4 acc[4][4] = {};
  for (int kt = 0; kt < K; kt += 32) {
    __syncthreads();
#pragma unroll
    for (int i = 0; i < 2; ++i) {
      int c = tid + (i << 8);              // 0..511
      int row = c >> 2, kc = (c & 3) << 3; // 4x16B chunks per 32-col row
      gload16(A + (size_t)(bm * 128 + row) * K + kt + kc, &As[(w * 64 + i * 256) * 8]);
      gload16(B + (size_t)(bn * 128 + row) * K + kt + kc, &Bs[(w * 64 + i * 256) * 8]);
    }
    __syncthreads();
    bf16x8 af[4], bfr[4];
#pragma unroll
    for (int mi = 0; mi < 4; ++mi)
      af[mi] = *(const bf16x8*)&As[(wm + mi * 16 + (lane & 15)) * 32 + ((lane >> 4) << 3)];
#pragma unroll
    for (int ni = 0; ni < 4; ++ni)
      bfr[ni] = *(const bf16x8*)&Bs[(wn + ni * 16 + (lane & 15)) * 32 + ((lane >> 4) << 3)];
#pragma unroll
    for (int mi = 0; mi < 4; ++mi)
#pragma unroll
      for (int ni = 0; ni < 4; ++ni)
        acc[mi][ni] = __builtin_amdgcn_mfma_f32_16x16x32_bf16(af[mi], bfr[ni], acc[mi][ni], 0, 0, 0);
  }
#pragma unroll
  for (int mi = 0; mi < 4; ++mi) {
#pragma unroll
    for (int ni = 0; ni < 4; ++ni) {
#pragma unroll
      for (int r = 0; r < 4; ++r) {
        int gm = bm * 128 + wm + mi * 16 + ((lane >> 4) << 2) + r;
        int gn = bn * 128 + wn + ni * 16 + (lane & 15);
        if (EPI == 0) {
          ((unsigned short*)C)[(size_t)gm * N + gn] = f2bf(acc[mi][ni][r]);
        } else {
          ((float*)C)[(size_t)gm * N + gn] = acc[mi][ni][r] + bias[gn];
        }
      }
    }
  }
}

// ---------------- RoPE + head split (+ V transpose) ----------------
// qkv[8192][1536] -> qh[bh][n][64], kh[bh][n][64], vt[bh][64][4096]  (all RoPE'd)
__global__ __launch_bounds__(256) void k_rope_split(const unsigned short* __restrict__ qkv,
                                                    const float* __restrict__ cosT,
                                                    const float* __restrict__ sinT,
                                                    unsigned short* __restrict__ qh,
                                                    unsigned short* __restrict__ kh,
                                                    unsigned short* __restrict__ vt) {
  __shared__ unsigned short vs[128][65];
  int nt = blockIdx.x, bh = blockIdx.y;
  int b = bh >> 3, h = bh & 7;
  int n0 = nt * 128;
  int t = threadIdx.x;
  int sub = t >> 3, cc = t & 7;
#pragma unroll
  for (int rr = 0; rr < 4; ++rr) {
    int row = rr * 32 + sub;
    int n = n0 + row;
    size_t base = ((size_t)(b * NSEQ + n)) * QKVN + h * 64 + cc * 8;
    const float* cb = cosT + ((size_t)(b * NSEQ + n)) * 64 + cc * 8;
    const float* sb = sinT + ((size_t)(b * NSEQ + n)) * 64 + cc * 8;
    float c[8], sn[8];
#pragma unroll
    for (int j = 0; j < 8; ++j) { c[j] = cb[j]; sn[j] = sb[j]; }
    bf16x8 qv = *(const bf16x8*)(qkv + base);
    bf16x8 kv = *(const bf16x8*)(qkv + base + 512);
    bf16x8 vv = *(const bf16x8*)(qkv + base + 1024);
    union { bf16x8 v; unsigned short u[8]; } yq, yk;
#pragma unroll
    for (int j = 0; j < 8; j += 2) {
      {
        float e = bf2f((unsigned short)qv[j]), o = bf2f((unsigned short)qv[j + 1]);
        yq.u[j]     = f2bf(e * c[j] - o * sn[j]);
        yq.u[j + 1] = f2bf(o * c[j + 1] + e * sn[j + 1]);
      }
      {
        float e = bf2f((unsigned short)kv[j]), o = bf2f((unsigned short)kv[j + 1]);
        yk.u[j]     = f2bf(e * c[j] - o * sn[j]);
        yk.u[j + 1] = f2bf(o * c[j + 1] + e * sn[j + 1]);
      }
      {
        float e = bf2f((unsigned short)vv[j]), o = bf2f((unsigned short)vv[j + 1]);
        vs[row][cc * 8 + j]     = f2bf(e * c[j] - o * sn[j]);
        vs[row][cc * 8 + j + 1] = f2bf(o * c[j + 1] + e * sn[j + 1]);
      }
    }
    *(bf16x8*)(qh + ((size_t)bh * NSEQ + n) * 64 + cc * 8) = yq.v;
    *(bf16x8*)(kh + ((size_t)bh * NSEQ + n) * 64 + cc * 8) = yk.v;
  }
  __syncthreads();
  int d = t >> 2, c4 = t & 3;
#pragma unroll
  for (int g = 0; g < 4; ++g) {
    union { bf16x8 v; unsigned short u[8]; } tv;
#pragma unroll
    for (int j = 0; j < 8; ++j) tv.u[j] = vs[c4 * 32 + g * 8 + j][d];
    *(bf16x8*)(vt + ((size_t)bh * 64 + d) * NSEQ + n0 + c4 * 32 + g * 8) = tv.v;
  }
}

// ---------------- Flash attention + inverse RoPE epilogue ----------------
// grid (64 q-tiles, 16 bh), 4 waves; wave owns 16 q rows; KV tile = 64 keys
__global__ __launch_bounds__(256) void k_attn(const unsigned short* __restrict__ Q,
                                              const unsigned short* __restrict__ Kg,
                                              const unsigned short* __restrict__ VT,
                                              const float* __restrict__ cosT,
                                              const float* __restrict__ sinT,
                                              unsigned short* __restrict__ AO) {
  __shared__ __align__(16) unsigned short Ks[64 * 64];
  __shared__ __align__(16) unsigned short Vs[64 * 64];  // [d][k]
  __shared__ __align__(16) unsigned short Ps[4][16 * 64];
  int nt = blockIdx.x, bh = blockIdx.y;
  int b = bh >> 3, h = bh & 7;
  int tid = threadIdx.x, lane = tid & 63, w = tid >> 6;
  int q0 = nt * 64 + w * 16;
  const unsigned short* Qb = Q + ((size_t)bh * NSEQ + q0 + (lane & 15)) * 64 + ((lane >> 4) << 3);
  bf16x8 qa0 = *(const bf16x8*)Qb;
  bf16x8 qa1 = *(const bf16x8*)(Qb + 32);
  const unsigned short* Kb = Kg + (size_t)bh * NSEQ * 64;
  const unsigned short* Vb = VT + (size_t)bh * 64 * NSEQ;
  f32x4 acc[4] = {};
  float m_run[4], l_run[4];
#pragma unroll
  for (int r = 0; r < 4; ++r) { m_run[r] = -1e30f; l_run[r] = 0.f; }

  for (int k0 = 0; k0 < NSEQ; k0 += 64) {
    __syncthreads();
#pragma unroll
    for (int i = 0; i < 2; ++i) {
      int c = tid + (i << 8);            // 0..511: row = c>>3, 16B chunk = c&7
      int row = c >> 3, cc = c & 7;
      bf16x8 kvk = *(const bf16x8*)(Kb + (size_t)(k0 + row) * 64 + (cc << 3));
      *(bf16x8*)((char*)Ks + swz(row, cc << 4)) = kvk;
      bf16x8 kvv = *(const bf16x8*)(Vb + (size_t)row * NSEQ + k0 + (cc << 3));
      *(bf16x8*)((char*)Vs + swz(row, cc << 4)) = kvv;
    }
    __syncthreads();
    // QK^T: 4 key sub-tiles of 16
    f32x4 s[4];
#pragma unroll
    for (int ni = 0; ni < 4; ++ni) {
      int krow = ni * 16 + (lane & 15);
      bf16x8 kb0 = *(const bf16x8*)((char*)Ks + swz(krow, (lane >> 4) << 4));
      bf16x8 kb1 = *(const bf16x8*)((char*)Ks + swz(krow, 64 + ((lane >> 4) << 4)));
      f32x4 t = {};
      t = __builtin_amdgcn_mfma_f32_16x16x32_bf16(qa0, kb0, t, 0, 0, 0);
      t = __builtin_amdgcn_mfma_f32_16x16x32_bf16(qa1, kb1, t, 0, 0, 0);
      s[ni] = t;
    }
    // online softmax (rows: (lane>>4)*4+r; cols across 16-lane groups)
    const float sc = 0.125f;
    float corr[4];
#pragma unroll
    for (int r = 0; r < 4; ++r) {
      float v = fmaxf(fmaxf(s[0][r], s[1][r]), fmaxf(s[2][r], s[3][r])) * sc;
      v = fmaxf(v, __shfl_xor(v, 1));
      v = fmaxf(v, __shfl_xor(v, 2));
      v = fmaxf(v, __shfl_xor(v, 4));
      v = fmaxf(v, __shfl_xor(v, 8));
      float mn = fmaxf(m_run[r], v);
      corr[r] = __expf(m_run[r] - mn);
      m_run[r] = mn;
    }
    char* pbase = (char*)&Ps[w][0];
#pragma unroll
    for (int r = 0; r < 4; ++r) {
      int prow = ((lane >> 4) << 2) + r;
      float rs = 0.f;
#pragma unroll
      for (int ni = 0; ni < 4; ++ni) {
        float p = __expf(s[ni][r] * sc - m_run[r]);
        rs += p;
        *(unsigned short*)(pbase + prow * 128 +
                           ((ni * 32 + ((lane & 15) << 1)) ^ ((prow & 7) << 4))) = f2bf(p);
      }
      rs += __shfl_xor(rs, 1);
      rs += __shfl_xor(rs, 2);
      rs += __shfl_xor(rs, 4);
      rs += __shfl_xor(rs, 8);
      l_run[r] = l_run[r] * corr[r] + rs;
#pragma unroll
      for (int di = 0; di < 4; ++di) acc[di][r] *= corr[r];
    }
    __syncthreads();  // P visible (also keeps waves phase-aligned)
    // PV: A = P (16x64), B^T = Vs rows d
    bf16x8 pa[2];
#pragma unroll
    for (int kk = 0; kk < 2; ++kk) {
      int prow = lane & 15;
      pa[kk] = *(const bf16x8*)(pbase + prow * 128 +
                                ((kk * 64 + ((lane >> 4) << 4)) ^ ((prow & 7) << 4)));
    }
#pragma unroll
    for (int di = 0; di < 4; ++di) {
#pragma unroll
      for (int kk = 0; kk < 2; ++kk) {
        int vrow = di * 16 + (lane & 15);
        bf16x8 vb = *(const bf16x8*)((char*)Vs + swz(vrow, kk * 64 + ((lane >> 4) << 4)));
        acc[di] = __builtin_amdgcn_mfma_f32_16x16x32_bf16(pa[kk], vb, acc[di], 0, 0, 0);
      }
    }
  }
  // epilogue: normalize + inverse RoPE + store to ao[b][n][h*64+d]
#pragma unroll
  for (int r = 0; r < 4; ++r) {
    int q = q0 + ((lane >> 4) << 2) + r;
    float inv = 1.f / l_run[r];
    const float* cb = cosT + ((size_t)b * NSEQ + q) * 64;
    const float* sb = sinT + ((size_t)b * NSEQ + q) * 64;
#pragma unroll
    for (int di = 0; di < 4; ++di) {
      int d = di * 16 + (lane & 15);
      float o = acc[di][r] * inv;
      float op = __shfl_xor(o, 1);
      float cv = cb[d], sv = sb[d];
      float res = (d & 1) ? (o * cv - op * sv) : (o * cv + op * sv);
      AO[((size_t)(b * NSEQ + q)) * DIM + h * 64 + d] = f2bf(res);
    }
  }
}

extern "C" void kernel_launch(void* const* d_in, const int* in_sizes, int n_in,
                              void* d_out, int out_size, void* d_ws, size_t ws_size,
                              hipStream_t stream) {
  const float* x    = (const float*)d_in[0];
  const float* rot  = (const float*)d_in[1];
  const float* lnw  = (const float*)d_in[2];
  const float* lnb  = (const float*)d_in[3];
  const float* wqkv = (const float*)d_in[4];
  const float* wout = (const float*)d_in[5];
  const float* bout = (const float*)d_in[6];
  float* out = (float*)d_out;

  char* ws = (char*)d_ws;
  const size_t MB = (size_t)1 << 20;
  float* cosT          = (float*)(ws + 0 * MB);        // 2 MB
  float* sinT          = (float*)(ws + 2 * MB);        // 2 MB
  unsigned short* wqkb = (unsigned short*)(ws + 4 * MB);   // 1.5 MB
  unsigned short* wob  = (unsigned short*)(ws + 6 * MB);   // 0.5 MB
  unsigned short* xn   = (unsigned short*)(ws + 8 * MB);   // 8 MB
  unsigned short* qkv  = (unsigned short*)(ws + 16 * MB);  // 24 MB
  unsigned short* ao   = (unsigned short*)(ws + 16 * MB);  // reuse (qkv dead after split)
  unsigned short* qh   = (unsigned short*)(ws + 40 * MB);  // 8 MB
  unsigned short* kh   = (unsigned short*)(ws + 48 * MB);  // 8 MB
  unsigned short* vt   = (unsigned short*)(ws + 56 * MB);  // 8 MB  (total 64 MB)

  k_tables<<<(BATCH * NSEQ * 64) / 256, 256, 0, stream>>>(rot, cosT, sinT);
  k_cvt<<<(QKVN * DIM + 255) / 256, 256, 0, stream>>>(wqkv, wqkb, QKVN * DIM);
  k_cvt<<<(DIM * DIM + 255) / 256, 256, 0, stream>>>(wout, wob, DIM * DIM);
  k_ln<<<NROWS / 4, 256, 0, stream>>>(x, lnw, lnb, xn);
  k_gemm<0><<<dim3(NROWS / 128, QKVN / 128), 256, 0, stream>>>(xn, wqkb, qkv, nullptr,
                                                               NROWS, QKVN, DIM);
  k_rope_split<<<dim3(NSEQ / 128, 16), 256, 0, stream>>>(qkv, cosT, sinT, qh, kh, vt);
  k_attn<<<dim3(NSEQ / 64, 16), 256, 0, stream>>>(qh, kh, vt, cosT, sinT, ao);
  k_gemm<1><<<dim3(NROWS / 128, DIM / 128), 256, 0, stream>>>(ao, wob, out, bout,
                                                              NROWS, DIM, DIM);
}